// Round 6
// baseline (292.536 us; speedup 1.0000x reference)
//
#include <hip/hip_runtime.h>
#include <hip/hip_bf16.h>

// B=4, S=2048, D=1024. q=relu(x Wq^T + bq) etc; out = softmax(q k^T) v.
// R10 = R6 + counted-vmcnt double-buffered mainloop.
// Diagnosis (corrected cycle model, R4/R6/R9 triangulation): the ~70% lost
// time is the __syncthreads() vmcnt(0) drain each K-step (full gld_lds
// latency, zero cover), not LDS bank conflicts (write-side constant 6.29M)
// and not raw LDS BW. Fix: 2x16KB LDS buffers, stage tile t+1 while
// computing t, s_waitcnt vmcnt(4) + raw s_barrier (NEVER vmcnt(0) in-loop).
// Invariant: 4 loads in flight at loop top; STAGE(t+1)->8; vmcnt(4) lands
// tile t; bar publishes cross-wave; reads; lgkmcnt(0)+sched_barrier+bar
// closes the read window before next iter's overwrite. VMCNT(0) at exit
// (in-flight LDS writes must not outlive the workgroup).
// Everything else identical to R6 (best passing: 265.3 us): BK=32 frags
// (low VGPR), fused V-transpose qkv epilogue, 1-wave softmax, exact grids.
//
// ws layout (128 MB):
//   [0,16)   q bf16           [16,32) k bf16
//   [48,64)  vt bf16 (written transposed by qkv z==2)
//   [64,128) logits fp32 (softmax overwrites rows in-place with bf16 probs)
//   xb bf16 aliases [64,80), Wb bf16 aliases [80,86) -- consumed by qkv
//   before qk writes logits (stream-ordered).

#define SEQ 2048
#define DIM 1024
#define NB 4
#define MTOT (NB * SEQ)   // 8192

typedef __attribute__((ext_vector_type(8))) short frag_ab;
typedef __attribute__((ext_vector_type(16))) float frag_c16;

__device__ __forceinline__ ushort f2bf(float f) {
    union { float f; unsigned u; } x; x.f = f;
    unsigned r = x.u + 0x7fffu + ((x.u >> 16) & 1u);  // RNE
    return (ushort)(r >> 16);
}

typedef __attribute__((address_space(1))) const unsigned int guint;
typedef __attribute__((address_space(3))) unsigned int luint;

__device__ __forceinline__ void gld_lds16(const void* g, void* l) {
    __builtin_amdgcn_global_load_lds((guint*)g, (luint*)l, 16, 0, 0);
}

__device__ __forceinline__ void bar() {
    asm volatile("" ::: "memory");
    __builtin_amdgcn_s_barrier();
    asm volatile("" ::: "memory");
}
#define VMCNT(n) asm volatile("s_waitcnt vmcnt(" #n ")" ::: "memory")

#define TB (128 * 32)   // one 128x32 bf16 tile buffer = 8 KB

// ---------------------------------------------------------------------------
// 128x128-tile bf16 MFMA mainloop, 32x32x16, BK=32, DOUBLE-buffered with
// counted vmcnt. A,B pre-offset to tile row 0, K-contiguous (B^T), lda/ldb
// multiples of 8, K multiple of 32. LDS: As/Bs each 2 x (128x32). Staging
// and swizzle identical to R4 (16B chunk cg of row r at physical cg ^
// ((r>>1)&3); per-wave 16-row slice, wave-uniform LDS dest). Wave w owns
// the 64x64 subtile (wm,wn) as 2x2 32x32 MFMA tiles. Per-acc K-order
// identical to R4/R6 -> identical numerics.
// ---------------------------------------------------------------------------
__device__ __forceinline__ void gemm_tiles(
    const ushort* __restrict__ A, size_t lda,
    const ushort* __restrict__ B, size_t ldb, int K,
    ushort* As, ushort* Bs, frag_c16 (&acc)[2][2])
{
    const int tid  = threadIdx.x;
    const int wave = tid >> 6;
    const int lane = tid & 63;
    const int l32  = lane & 31;
    const int half = lane >> 5;
    const int sr = wave * 16 + (lane >> 2);   // staging row (within 64-row half)
    const int sc = lane & 3;                  // staging physical chunk slot
    const int wm = (wave & 1) * 64;
    const int wn = (wave >> 1) * 64;
    const int nkt = K >> 5;

    // stage tile kt into buffer b (4 gld_lds16 per thread)
    #define STAGE_TILE(kt, b) do {                                          \
        int k0_ = (kt) << 5;                                                \
        _Pragma("unroll")                                                   \
        for (int j = 0; j < 2; ++j) {                                       \
            int row = j * 64 + sr;                                          \
            int cg  = sc ^ ((row >> 1) & 3);                                \
            ushort* la = As + (b) * TB + (j * 64 + wave * 16) * 32;         \
            ushort* lb = Bs + (b) * TB + (j * 64 + wave * 16) * 32;         \
            gld_lds16(A + (size_t)row * lda + k0_ + cg * 8, la);            \
            gld_lds16(B + (size_t)row * ldb + k0_ + cg * 8, lb);            \
        }                                                                   \
    } while (0)

    STAGE_TILE(0, 0);                 // outstanding: 4 (tile 0)
    for (int t = 0; t < nkt; ++t) {
        const int c = t & 1;
        // WAR-safe: buf c^1's readers (iter t-1) closed at its 2nd barrier.
        // Tail stages a garbage repeat of the last tile (in-bounds, never
        // consumed) to keep the vmcnt count uniform.
        int tn = t + 1 < nkt ? t + 1 : nkt - 1;
        STAGE_TILE(tn, c ^ 1);        // outstanding: 8
        VMCNT(4);                     // tile t's 4 landed (this wave)
        bar();                        // -> tile t globally visible

        const ushort* Ac = As + c * TB;
        const ushort* Bc = Bs + c * TB;
        frag_ab af[2][2], bfr[2][2];
        #pragma unroll
        for (int mi = 0; mi < 2; ++mi) {
            int row = wm + mi * 32 + l32;
            int sw = (row >> 1) & 3;
            #pragma unroll
            for (int h = 0; h < 2; ++h) {
                int cc = (h * 2 + half) ^ sw;
                af[mi][h] = *(const frag_ab*)&Ac[row * 32 + cc * 8];
            }
        }
        #pragma unroll
        for (int ni = 0; ni < 2; ++ni) {
            int row = wn + ni * 32 + l32;
            int sw = (row >> 1) & 3;
            #pragma unroll
            for (int h = 0; h < 2; ++h) {
                int cc = (h * 2 + half) ^ sw;
                bfr[ni][h] = *(const frag_ab*)&Bc[row * 32 + cc * 8];
            }
        }
        asm volatile("s_waitcnt lgkmcnt(0)" ::: "memory");
        __builtin_amdgcn_sched_barrier(0);
        bar();                        // reads closed -> buf c writable next iter

        #pragma unroll
        for (int h = 0; h < 2; ++h)
            #pragma unroll
            for (int mi = 0; mi < 2; ++mi)
                #pragma unroll
                for (int ni = 0; ni < 2; ++ni)
                    acc[mi][ni] = __builtin_amdgcn_mfma_f32_32x32x16_bf16(
                        af[mi][h], bfr[ni][h], acc[mi][ni], 0, 0, 0);
    }
    VMCNT(0);   // don't retire the workgroup with LDS writes in flight
    #undef STAGE_TILE
}

// C/D layout (32x32): col = lane&31, row = (reg&3) + 8*(reg>>2) + 4*(lane>>5)

// ---------------------------------------------------------------------------
// fp32 -> bf16 converter, x + 3 weights in one launch (memory-bound)
// ---------------------------------------------------------------------------
#define NX4 (MTOT * DIM / 4)          // 2M float4 for x
#define NW4 (DIM * DIM / 4)           // 256K float4 per W
__global__ __launch_bounds__(256) void cvt_kernel(
    const float* __restrict__ x,
    const float* __restrict__ Wq, const float* __restrict__ Wk,
    const float* __restrict__ Wv,
    ushort* __restrict__ xb, ushort* __restrict__ Wb)
{
    size_t i = (size_t)blockIdx.x * 256 + threadIdx.x;
    const float* src; ushort* dst; size_t idx;
    if (i < NX4) { src = x; dst = xb; idx = i; }
    else {
        size_t j = i - NX4;
        int w = (int)(j >> 18);               // j / NW4
        idx = j & (NW4 - 1);
        src = w == 0 ? Wq : (w == 1 ? Wk : Wv);
        dst = Wb + (size_t)w * DIM * DIM;
    }
    float4 f = ((const float4*)src)[idx];
    ushort4 u; u.x = f2bf(f.x); u.y = f2bf(f.y); u.z = f2bf(f.z); u.w = f2bf(f.w);
    ((ushort4*)dst)[idx] = u;
}

// ---------------------------------------------------------------------------
// Kernel 1: q/k/v = relu(x W^T + b) -> bf16.  grid (64, 8, 3), block 256.
// z==0 -> q row-major, z==1 -> k row-major, z==2 -> V written TRANSPOSED
// into vt[bz][o][s] (r&3 packs 4 consecutive s -> ushort4 stores).
// ---------------------------------------------------------------------------
__global__ __launch_bounds__(256) void qkv_kernel(
    const ushort* __restrict__ xb, const ushort* __restrict__ Wb,
    const float* __restrict__ bq, const float* __restrict__ bk,
    const float* __restrict__ bv,
    ushort* __restrict__ q, ushort* __restrict__ kk, ushort* __restrict__ vt)
{
    const float* bias;
    if (blockIdx.z == 0)      bias = bq;
    else if (blockIdx.z == 1) bias = bk;
    else                      bias = bv;
    const ushort* W = Wb + (size_t)blockIdx.z * DIM * DIM;

    __shared__ ushort As[2 * TB];
    __shared__ ushort Bs[2 * TB];

    const int tid  = threadIdx.x;
    const int wave = tid >> 6;
    const int lane = tid & 63;
    const int l32  = lane & 31;
    const int half = lane >> 5;
    const int m0 = blockIdx.x * 128;
    const int n0 = blockIdx.y * 128;
    const int wm = (wave & 1) * 64;
    const int wn = (wave >> 1) * 64;

    frag_c16 acc[2][2] = {};
    gemm_tiles(xb + (size_t)m0 * DIM, DIM, W + (size_t)n0 * DIM, DIM, DIM,
               As, Bs, acc);

    if (blockIdx.z == 2) {
        // vt[bz][col][s]; tile rows never straddle a batch (128 | 2048)
        const int bz = m0 >> 11;
        const int sb = (m0 & (SEQ - 1)) + wm;
        #pragma unroll
        for (int ni = 0; ni < 2; ++ni) {
            int col = n0 + wn + ni * 32 + l32;
            float bb = bias[col];
            ushort* vrow = vt + ((size_t)(bz * DIM + col)) * SEQ;
            #pragma unroll
            for (int mi = 0; mi < 2; ++mi)
                #pragma unroll
                for (int g = 0; g < 4; ++g) {
                    int s0 = sb + mi * 32 + 8 * g + 4 * half;
                    ushort4 u;
                    #pragma unroll
                    for (int j = 0; j < 4; ++j) {
                        float val = acc[mi][ni][4 * g + j] + bb;
                        val = val > 0.0f ? val : 0.0f;
                        ((ushort*)&u)[j] = f2bf(val);
                    }
                    *(ushort4*)&vrow[s0] = u;
                }
        }
    } else {
        ushort* out = blockIdx.z == 0 ? q : kk;
        #pragma unroll
        for (int ni = 0; ni < 2; ++ni) {
            int col = n0 + wn + ni * 32 + l32;
            float bb = bias[col];
            #pragma unroll
            for (int mi = 0; mi < 2; ++mi)
                #pragma unroll
                for (int r = 0; r < 16; ++r) {
                    int row = m0 + wm + mi * 32 + (r & 3) + 8 * (r >> 2) + 4 * half;
                    float val = acc[mi][ni][r] + bb;
                    val = val > 0.0f ? val : 0.0f;
                    out[(size_t)row * DIM + col] = f2bf(val);
                }
        }
    }
}

// ---------------------------------------------------------------------------
// Kernel 3: logits = q k^T (fp32).  grid (16,16,4)
// ---------------------------------------------------------------------------
__global__ __launch_bounds__(256) void qk_kernel(
    const ushort* __restrict__ q, const ushort* __restrict__ kk,
    float* __restrict__ logits)
{
    __shared__ ushort As[2 * TB];
    __shared__ ushort Bs[2 * TB];

    const int tid  = threadIdx.x;
    const int wave = tid >> 6;
    const int lane = tid & 63;
    const int l32  = lane & 31;
    const int half = lane >> 5;
    const int bz = blockIdx.z;
    const int m0 = blockIdx.x * 128;
    const int n0 = blockIdx.y * 128;
    const int wm = (wave & 1) * 64;
    const int wn = (wave >> 1) * 64;
    const size_t base = (size_t)bz * SEQ;

    frag_c16 acc[2][2] = {};
    gemm_tiles(q + (base + m0) * DIM, DIM, kk + (base + n0) * DIM, DIM, DIM,
               As, Bs, acc);

    #pragma unroll
    for (int mi = 0; mi < 2; ++mi)
        #pragma unroll
        for (int r = 0; r < 16; ++r) {
            int row = m0 + wm + mi * 32 + (r & 3) + 8 * (r >> 2) + 4 * half;
            #pragma unroll
            for (int ni = 0; ni < 2; ++ni) {
                int col = n0 + wn + ni * 32 + l32;
                logits[(base + row) * SEQ + col] = acc[mi][ni][r];
            }
        }
}

// ---------------------------------------------------------------------------
// Kernel 4: row softmax over 2048 fp32, write bf16 probs in-place.
// 1 wave per row, 4 rows per block, no LDS / no barriers.
// ---------------------------------------------------------------------------
__global__ __launch_bounds__(256) void softmax_kernel(float* __restrict__ logits)
{
    const int row  = blockIdx.x * 4 + (threadIdx.x >> 6);
    const int lane = threadIdx.x & 63;
    float* p = logits + (size_t)row * SEQ;

    float4 x[8];
    #pragma unroll
    for (int i = 0; i < 8; ++i) x[i] = ((const float4*)p)[lane + 64 * i];

    float m = -3.4e38f;
    #pragma unroll
    for (int i = 0; i < 8; ++i)
        m = fmaxf(m, fmaxf(fmaxf(x[i].x, x[i].y), fmaxf(x[i].z, x[i].w)));
    #pragma unroll
    for (int off = 32; off; off >>= 1) m = fmaxf(m, __shfl_xor(m, off, 64));

    float s = 0.0f;
    #pragma unroll
    for (int i = 0; i < 8; ++i) {
        x[i].x = __expf(x[i].x - m); x[i].y = __expf(x[i].y - m);
        x[i].z = __expf(x[i].z - m); x[i].w = __expf(x[i].w - m);
        s += (x[i].x + x[i].y) + (x[i].z + x[i].w);
    }
    #pragma unroll
    for (int off = 32; off; off >>= 1) s += __shfl_xor(s, off, 64);
    float inv = 1.0f / s;

    ushort* o = (ushort*)p;
    #pragma unroll
    for (int i = 0; i < 8; ++i) {
        ushort4 u;
        u.x = f2bf(x[i].x * inv); u.y = f2bf(x[i].y * inv);
        u.z = f2bf(x[i].z * inv); u.w = f2bf(x[i].w * inv);
        ((ushort4*)o)[lane + 64 * i] = u;
    }
}

// ---------------------------------------------------------------------------
// Kernel 5: out = P vt^T (fp32). P rows stride 4096 ushorts. grid (16,8,4)
// ---------------------------------------------------------------------------
__global__ __launch_bounds__(256) void pv_kernel(
    const ushort* __restrict__ probs, const ushort* __restrict__ vt,
    float* __restrict__ out)
{
    __shared__ ushort As[2 * TB];
    __shared__ ushort Bs[2 * TB];

    const int tid  = threadIdx.x;
    const int wave = tid >> 6;
    const int lane = tid & 63;
    const int l32  = lane & 31;
    const int half = lane >> 5;
    const int bz = blockIdx.z;
    const int m0 = blockIdx.x * 128;
    const int n0 = blockIdx.y * 128;
    const int wm = (wave & 1) * 64;
    const int wn = (wave >> 1) * 64;

    frag_c16 acc[2][2] = {};
    gemm_tiles(probs + ((size_t)(bz * SEQ + m0)) * 4096, 4096,
               vt + ((size_t)(bz * DIM + n0)) * SEQ, SEQ, SEQ,
               As, Bs, acc);

    #pragma unroll
    for (int mi = 0; mi < 2; ++mi)
        #pragma unroll
        for (int r = 0; r < 16; ++r) {
            int row = m0 + wm + mi * 32 + (r & 3) + 8 * (r >> 2) + 4 * half;
            #pragma unroll
            for (int ni = 0; ni < 2; ++ni) {
                int col = n0 + wn + ni * 32 + l32;
                out[((size_t)(bz * SEQ + row)) * DIM + col] = acc[mi][ni][r];
            }
        }
}

// ---------------------------------------------------------------------------
extern "C" void kernel_launch(void* const* d_in, const int* in_sizes, int n_in,
                              void* d_out, int out_size, void* d_ws, size_t ws_size,
                              hipStream_t stream)
{
    const float* x  = (const float*)d_in[0];
    const float* Wq = (const float*)d_in[1];
    const float* bq = (const float*)d_in[2];
    const float* Wk = (const float*)d_in[3];
    const float* bk = (const float*)d_in[4];
    const float* Wv = (const float*)d_in[5];
    const float* bv = (const float*)d_in[6];
    float* out = (float*)d_out;

    char* ws = (char*)d_ws;
    ushort* q      = (ushort*)(ws);                           // 16 MB
    ushort* kk     = (ushort*)(ws + ((size_t)16 << 20));      // 16 MB
    ushort* vt     = (ushort*)(ws + ((size_t)48 << 20));      // 16 MB
    float*  logits = (float*) (ws + ((size_t)64 << 20));      // 64 MB
    ushort* xb     = (ushort*)(ws + ((size_t)64 << 20));      // aliases logits
    ushort* Wb     = (ushort*)(ws + ((size_t)80 << 20));      // aliases logits

    cvt_kernel<<<dim3((NX4 + 3 * NW4) / 256), 256, 0, stream>>>(
        x, Wq, Wk, Wv, xb, Wb);

    qkv_kernel<<<dim3(MTOT / 128, DIM / 128, 3), 256, 0, stream>>>(
        xb, Wb, bq, bk, bv, q, kk, vt);
    qk_kernel<<<dim3(SEQ / 128, SEQ / 128, NB), 256, 0, stream>>>(q, kk, logits);
    softmax_kernel<<<NB * SEQ / 4, 256, 0, stream>>>(logits);
    pv_kernel<<<dim3(SEQ / 128, DIM / 128, NB), 256, 0, stream>>>(
        (const ushort*)logits, vt, out);
}

// Round 7
// 262.320 us; speedup vs baseline: 1.1152x; 1.1152x over previous
//
#include <hip/hip_runtime.h>
#include <hip/hip_bf16.h>

// B=4, S=2048, D=1024. q=relu(x Wq^T + bq) etc; out = softmax(q k^T) v.
// R11 = R6 (best passing, 265.3us) + the MINIMAL counted-vmcnt change:
// double-buffered LDS, stage-next-tile-first, s_waitcnt vmcnt(8) + raw
// s_barrier instead of __syncthreads' vmcnt(0) drain. Crucially NO forced
// lgkmcnt(0)/sched_barrier between ds_reads and MFMAs (R10's bug: pinning
// reads serialized ~1000cy of LDS latency per K-step; compiler's own
// lgkmcnt(4/3/1/0) interleave is near-optimal -- let it work).
//   per iter: STAGE(t+1 -> buf^1) [8 gld, 16 outstanding]; VMCNT(8) [tile t
//   landed, never 0 in-loop]; bar; ds_read+MFMA compiler-scheduled; bar
//   [reads retired via MFMA data-dep -> next iter may overwrite].
// Everything else byte-identical to R6: BK=64 core w/ 3-bit XOR chunk
// swizzle, fused V-transpose qkv epilogue, 1-wave softmax, exact grids.
//
// ws layout (128 MB):
//   [0,16)   q bf16           [16,32) k bf16
//   [48,64)  vt bf16 (written transposed by qkv z==2)
//   [64,128) logits fp32 (softmax overwrites rows in-place with bf16 probs)
//   xb bf16 aliases [64,80), Wb bf16 aliases [80,86) -- consumed by qkv
//   before qk writes logits (stream-ordered).

#define SEQ 2048
#define DIM 1024
#define NB 4
#define MTOT (NB * SEQ)   // 8192

typedef __attribute__((ext_vector_type(8))) short frag_ab;
typedef __attribute__((ext_vector_type(16))) float frag_c16;

__device__ __forceinline__ ushort f2bf(float f) {
    union { float f; unsigned u; } x; x.f = f;
    unsigned r = x.u + 0x7fffu + ((x.u >> 16) & 1u);  // RNE
    return (ushort)(r >> 16);
}

typedef __attribute__((address_space(1))) const unsigned int guint;
typedef __attribute__((address_space(3))) unsigned int luint;

__device__ __forceinline__ void gld_lds16(const void* g, void* l) {
    __builtin_amdgcn_global_load_lds((guint*)g, (luint*)l, 16, 0, 0);
}

__device__ __forceinline__ void bar() {
    asm volatile("" ::: "memory");
    __builtin_amdgcn_s_barrier();
    asm volatile("" ::: "memory");
}
#define VMCNT(n) asm volatile("s_waitcnt vmcnt(" #n ")" ::: "memory")

#define TB (128 * 64)   // one 128x64 bf16 tile buffer = 16 KB

// ---------------------------------------------------------------------------
// 128x128-tile bf16 MFMA mainloop, 32x32x16, BK=64, double-buffered with
// counted vmcnt. A,B pre-offset to tile row 0, K-contiguous (B^T), lda/ldb
// multiples of 8, K multiple of 64. Staging/swizzle identical to R6: per
// wave 4 groups of 8 rows; logical 16B chunk cl = cp ^ (row&7) fetched from
// pre-swizzled global source, LDS dest linear; read side applies the same
// involution (conflict-free: each 8-lane group covers all 8 chunks).
// Wave w owns the 64x64 subtile (wm,wn) as 2x2 32x32 MFMA tiles.
// Per-acc K-order identical to R6 -> identical numerics.
// ---------------------------------------------------------------------------
__device__ __forceinline__ void gemm_tiles(
    const ushort* __restrict__ A, size_t lda,
    const ushort* __restrict__ B, size_t ldb, int K,
    ushort* As, ushort* Bs, frag_c16 (&acc)[2][2])
{
    const int tid  = threadIdx.x;
    const int wave = tid >> 6;
    const int lane = tid & 63;
    const int l32  = lane & 31;
    const int half = lane >> 5;
    const int rin  = lane >> 3;      // row within an 8-row group
    const int cp   = lane & 7;       // physical 16B chunk slot
    const int cl   = cp ^ rin;       // logical chunk (XOR involution)
    const int wm = (wave & 1) * 64;
    const int wn = (wave >> 1) * 64;
    const int nkt = K >> 6;

    // stage tile kt into buffer b: 8 gld_lds16 per thread
    #define STAGE_TILE(kt, b) do {                                          \
        int k0_ = (kt) << 6;                                                \
        _Pragma("unroll")                                                   \
        for (int g = 0; g < 4; ++g) {                                       \
            int qc  = g * 4 + wave;                                         \
            int row = qc * 8 + rin;      /* row&7 == rin */                 \
            gld_lds16(A + (size_t)row * lda + k0_ + cl * 8,                 \
                      As + (b) * TB + qc * 512);                            \
            gld_lds16(B + (size_t)row * ldb + k0_ + cl * 8,                 \
                      Bs + (b) * TB + qc * 512);                            \
        }                                                                   \
    } while (0)

    STAGE_TILE(0, 0);                 // outstanding: 8 (tile 0)
    for (int t = 0; t < nkt; ++t) {
        const int c = t & 1;
        // Tail stages a garbage repeat of the last tile (in-bounds, never
        // consumed) so the vmcnt count stays uniform.
        int tn = t + 1 < nkt ? t + 1 : nkt - 1;
        STAGE_TILE(tn, c ^ 1);        // outstanding: 16
        VMCNT(8);                     // tile t's 8 landed (this wave's slice)
        bar();                        // -> tile t globally visible

        const ushort* Ac = As + c * TB;
        const ushort* Bc = Bs + c * TB;
        frag_ab af[2][4], bf[2][4];
        #pragma unroll
        for (int mi = 0; mi < 2; ++mi) {
            int row = wm + mi * 32 + l32;
            int sw = row & 7;
            #pragma unroll
            for (int ks = 0; ks < 4; ++ks) {
                int cc = (ks * 2 + half) ^ sw;
                af[mi][ks] = *(const frag_ab*)&Ac[row * 64 + cc * 8];
            }
        }
        #pragma unroll
        for (int ni = 0; ni < 2; ++ni) {
            int row = wn + ni * 32 + l32;
            int sw = row & 7;
            #pragma unroll
            for (int ks = 0; ks < 4; ++ks) {
                int cc = (ks * 2 + half) ^ sw;
                bf[ni][ks] = *(const frag_ab*)&Bc[row * 64 + cc * 8];
            }
        }
        #pragma unroll
        for (int ks = 0; ks < 4; ++ks)
            #pragma unroll
            for (int mi = 0; mi < 2; ++mi)
                #pragma unroll
                for (int ni = 0; ni < 2; ++ni)
                    acc[mi][ni] = __builtin_amdgcn_mfma_f32_32x32x16_bf16(
                        af[mi][ks], bf[ni][ks], acc[mi][ni], 0, 0, 0);
        bar();   // last MFMA's lgkmcnt implies all reads of buf c retired
    }
    VMCNT(0);   // don't retire the workgroup with LDS writes in flight
    #undef STAGE_TILE
}

// C/D layout (32x32): col = lane&31, row = (reg&3) + 8*(reg>>2) + 4*(lane>>5)

// ---------------------------------------------------------------------------
// fp32 -> bf16 converter, x + 3 weights in one launch (memory-bound)
// ---------------------------------------------------------------------------
#define NX4 (MTOT * DIM / 4)          // 2M float4 for x
#define NW4 (DIM * DIM / 4)           // 256K float4 per W
__global__ __launch_bounds__(256) void cvt_kernel(
    const float* __restrict__ x,
    const float* __restrict__ Wq, const float* __restrict__ Wk,
    const float* __restrict__ Wv,
    ushort* __restrict__ xb, ushort* __restrict__ Wb)
{
    size_t i = (size_t)blockIdx.x * 256 + threadIdx.x;
    const float* src; ushort* dst; size_t idx;
    if (i < NX4) { src = x; dst = xb; idx = i; }
    else {
        size_t j = i - NX4;
        int w = (int)(j >> 18);               // j / NW4
        idx = j & (NW4 - 1);
        src = w == 0 ? Wq : (w == 1 ? Wk : Wv);
        dst = Wb + (size_t)w * DIM * DIM;
    }
    float4 f = ((const float4*)src)[idx];
    ushort4 u; u.x = f2bf(f.x); u.y = f2bf(f.y); u.z = f2bf(f.z); u.w = f2bf(f.w);
    ((ushort4*)dst)[idx] = u;
}

// ---------------------------------------------------------------------------
// Kernel 1: q/k/v = relu(x W^T + b) -> bf16.  grid (64, 8, 3), block 256.
// z==0 -> q row-major, z==1 -> k row-major, z==2 -> V written TRANSPOSED
// into vt[bz][o][s] (r&3 packs 4 consecutive s -> ushort4 stores).
// ---------------------------------------------------------------------------
__global__ __launch_bounds__(256) void qkv_kernel(
    const ushort* __restrict__ xb, const ushort* __restrict__ Wb,
    const float* __restrict__ bq, const float* __restrict__ bk,
    const float* __restrict__ bv,
    ushort* __restrict__ q, ushort* __restrict__ kk, ushort* __restrict__ vt)
{
    const float* bias;
    if (blockIdx.z == 0)      bias = bq;
    else if (blockIdx.z == 1) bias = bk;
    else                      bias = bv;
    const ushort* W = Wb + (size_t)blockIdx.z * DIM * DIM;

    __shared__ ushort As[2 * TB];
    __shared__ ushort Bs[2 * TB];

    const int tid  = threadIdx.x;
    const int wave = tid >> 6;
    const int lane = tid & 63;
    const int l32  = lane & 31;
    const int half = lane >> 5;
    const int m0 = blockIdx.x * 128;
    const int n0 = blockIdx.y * 128;
    const int wm = (wave & 1) * 64;
    const int wn = (wave >> 1) * 64;

    frag_c16 acc[2][2] = {};
    gemm_tiles(xb + (size_t)m0 * DIM, DIM, W + (size_t)n0 * DIM, DIM, DIM,
               As, Bs, acc);

    if (blockIdx.z == 2) {
        // vt[bz][col][s]; tile rows never straddle a batch (128 | 2048)
        const int bz = m0 >> 11;
        const int sb = (m0 & (SEQ - 1)) + wm;
        #pragma unroll
        for (int ni = 0; ni < 2; ++ni) {
            int col = n0 + wn + ni * 32 + l32;
            float bb = bias[col];
            ushort* vrow = vt + ((size_t)(bz * DIM + col)) * SEQ;
            #pragma unroll
            for (int mi = 0; mi < 2; ++mi)
                #pragma unroll
                for (int g = 0; g < 4; ++g) {
                    int s0 = sb + mi * 32 + 8 * g + 4 * half;
                    ushort4 u;
                    #pragma unroll
                    for (int j = 0; j < 4; ++j) {
                        float val = acc[mi][ni][4 * g + j] + bb;
                        val = val > 0.0f ? val : 0.0f;
                        ((ushort*)&u)[j] = f2bf(val);
                    }
                    *(ushort4*)&vrow[s0] = u;
                }
        }
    } else {
        ushort* out = blockIdx.z == 0 ? q : kk;
        #pragma unroll
        for (int ni = 0; ni < 2; ++ni) {
            int col = n0 + wn + ni * 32 + l32;
            float bb = bias[col];
            #pragma unroll
            for (int mi = 0; mi < 2; ++mi)
                #pragma unroll
                for (int r = 0; r < 16; ++r) {
                    int row = m0 + wm + mi * 32 + (r & 3) + 8 * (r >> 2) + 4 * half;
                    float val = acc[mi][ni][r] + bb;
                    val = val > 0.0f ? val : 0.0f;
                    out[(size_t)row * DIM + col] = f2bf(val);
                }
        }
    }
}

// ---------------------------------------------------------------------------
// Kernel 3: logits = q k^T (fp32).  grid (16,16,4)
// ---------------------------------------------------------------------------
__global__ __launch_bounds__(256) void qk_kernel(
    const ushort* __restrict__ q, const ushort* __restrict__ kk,
    float* __restrict__ logits)
{
    __shared__ ushort As[2 * TB];
    __shared__ ushort Bs[2 * TB];

    const int tid  = threadIdx.x;
    const int wave = tid >> 6;
    const int lane = tid & 63;
    const int l32  = lane & 31;
    const int half = lane >> 5;
    const int bz = blockIdx.z;
    const int m0 = blockIdx.x * 128;
    const int n0 = blockIdx.y * 128;
    const int wm = (wave & 1) * 64;
    const int wn = (wave >> 1) * 64;
    const size_t base = (size_t)bz * SEQ;

    frag_c16 acc[2][2] = {};
    gemm_tiles(q + (base + m0) * DIM, DIM, kk + (base + n0) * DIM, DIM, DIM,
               As, Bs, acc);

    #pragma unroll
    for (int mi = 0; mi < 2; ++mi)
        #pragma unroll
        for (int r = 0; r < 16; ++r) {
            int row = m0 + wm + mi * 32 + (r & 3) + 8 * (r >> 2) + 4 * half;
            #pragma unroll
            for (int ni = 0; ni < 2; ++ni) {
                int col = n0 + wn + ni * 32 + l32;
                logits[(base + row) * SEQ + col] = acc[mi][ni][r];
            }
        }
}

// ---------------------------------------------------------------------------
// Kernel 4: row softmax over 2048 fp32, write bf16 probs in-place.
// 1 wave per row, 4 rows per block, no LDS / no barriers.
// ---------------------------------------------------------------------------
__global__ __launch_bounds__(256) void softmax_kernel(float* __restrict__ logits)
{
    const int row  = blockIdx.x * 4 + (threadIdx.x >> 6);
    const int lane = threadIdx.x & 63;
    float* p = logits + (size_t)row * SEQ;

    float4 x[8];
    #pragma unroll
    for (int i = 0; i < 8; ++i) x[i] = ((const float4*)p)[lane + 64 * i];

    float m = -3.4e38f;
    #pragma unroll
    for (int i = 0; i < 8; ++i)
        m = fmaxf(m, fmaxf(fmaxf(x[i].x, x[i].y), fmaxf(x[i].z, x[i].w)));
    #pragma unroll
    for (int off = 32; off; off >>= 1) m = fmaxf(m, __shfl_xor(m, off, 64));

    float s = 0.0f;
    #pragma unroll
    for (int i = 0; i < 8; ++i) {
        x[i].x = __expf(x[i].x - m); x[i].y = __expf(x[i].y - m);
        x[i].z = __expf(x[i].z - m); x[i].w = __expf(x[i].w - m);
        s += (x[i].x + x[i].y) + (x[i].z + x[i].w);
    }
    #pragma unroll
    for (int off = 32; off; off >>= 1) s += __shfl_xor(s, off, 64);
    float inv = 1.0f / s;

    ushort* o = (ushort*)p;
    #pragma unroll
    for (int i = 0; i < 8; ++i) {
        ushort4 u;
        u.x = f2bf(x[i].x * inv); u.y = f2bf(x[i].y * inv);
        u.z = f2bf(x[i].z * inv); u.w = f2bf(x[i].w * inv);
        ((ushort4*)o)[lane + 64 * i] = u;
    }
}

// ---------------------------------------------------------------------------
// Kernel 5: out = P vt^T (fp32). P rows stride 4096 ushorts. grid (16,8,4)
// ---------------------------------------------------------------------------
__global__ __launch_bounds__(256) void pv_kernel(
    const ushort* __restrict__ probs, const ushort* __restrict__ vt,
    float* __restrict__ out)
{
    __shared__ ushort As[2 * TB];
    __shared__ ushort Bs[2 * TB];

    const int tid  = threadIdx.x;
    const int wave = tid >> 6;
    const int lane = tid & 63;
    const int l32  = lane & 31;
    const int half = lane >> 5;
    const int bz = blockIdx.z;
    const int m0 = blockIdx.x * 128;
    const int n0 = blockIdx.y * 128;
    const int wm = (wave & 1) * 64;
    const int wn = (wave >> 1) * 64;

    frag_c16 acc[2][2] = {};
    gemm_tiles(probs + ((size_t)(bz * SEQ + m0)) * 4096, 4096,
               vt + ((size_t)(bz * DIM + n0)) * SEQ, SEQ, SEQ,
               As, Bs, acc);

    #pragma unroll
    for (int mi = 0; mi < 2; ++mi)
        #pragma unroll
        for (int r = 0; r < 16; ++r) {
            int row = m0 + wm + mi * 32 + (r & 3) + 8 * (r >> 2) + 4 * half;
            #pragma unroll
            for (int ni = 0; ni < 2; ++ni) {
                int col = n0 + wn + ni * 32 + l32;
                out[((size_t)(bz * SEQ + row)) * DIM + col] = acc[mi][ni][r];
            }
        }
}

// ---------------------------------------------------------------------------
extern "C" void kernel_launch(void* const* d_in, const int* in_sizes, int n_in,
                              void* d_out, int out_size, void* d_ws, size_t ws_size,
                              hipStream_t stream)
{
    const float* x  = (const float*)d_in[0];
    const float* Wq = (const float*)d_in[1];
    const float* bq = (const float*)d_in[2];
    const float* Wk = (const float*)d_in[3];
    const float* bk = (const float*)d_in[4];
    const float* Wv = (const float*)d_in[5];
    const float* bv = (const float*)d_in[6];
    float* out = (float*)d_out;

    char* ws = (char*)d_ws;
    ushort* q      = (ushort*)(ws);                           // 16 MB
    ushort* kk     = (ushort*)(ws + ((size_t)16 << 20));      // 16 MB
    ushort* vt     = (ushort*)(ws + ((size_t)48 << 20));      // 16 MB
    float*  logits = (float*) (ws + ((size_t)64 << 20));      // 64 MB
    ushort* xb     = (ushort*)(ws + ((size_t)64 << 20));      // aliases logits
    ushort* Wb     = (ushort*)(ws + ((size_t)80 << 20));      // aliases logits

    cvt_kernel<<<dim3((NX4 + 3 * NW4) / 256), 256, 0, stream>>>(
        x, Wq, Wk, Wv, xb, Wb);

    qkv_kernel<<<dim3(MTOT / 128, DIM / 128, 3), 256, 0, stream>>>(
        xb, Wb, bq, bk, bv, q, kk, vt);
    qk_kernel<<<dim3(SEQ / 128, SEQ / 128, NB), 256, 0, stream>>>(q, kk, logits);
    softmax_kernel<<<NB * SEQ / 4, 256, 0, stream>>>(logits);
    pv_kernel<<<dim3(SEQ / 128, DIM / 128, NB), 256, 0, stream>>>(
        (const ushort*)logits, vt, out);
}